// Round 11
// baseline (349.168 us; speedup 1.0000x reference)
//
#include <hip/hip_runtime.h>
#include <hip/hip_bf16.h>
#include <stdint.h>

#define N_TOK 16384
#define D_IN  2048
#define D_HID 2048

typedef __attribute__((ext_vector_type(8))) short  bf16x8;
typedef __attribute__((ext_vector_type(4))) float  f32x4;
typedef __attribute__((ext_vector_type(8))) unsigned short u16x8;

__device__ __forceinline__ unsigned short f2bf(float f) {
    unsigned int u = __float_as_uint(f);
    u = (u + 0x7FFFu + ((u >> 16) & 1u)) >> 16;
    return (unsigned short)u;
}

// ---------------------------------------------------------------- gate ----
__global__ void gate_kernel(const float* __restrict__ x,
                            const float* __restrict__ Wg,
                            const float* __restrict__ bg,
                            float* __restrict__ s12,
                            int* __restrict__ eidx) {
    const int token = blockIdx.x * 4 + (threadIdx.x >> 6);
    const int lane  = threadIdx.x & 63;
    const float* xr = x + (size_t)token * D_IN;

    float acc[8];
#pragma unroll
    for (int e = 0; e < 8; ++e) acc[e] = 0.f;

    for (int i = lane; i < D_IN; i += 64) {
        float xv = xr[i];
        const float4* wr = (const float4*)(Wg + (size_t)i * 8);
        float4 w0 = wr[0], w1 = wr[1];
        acc[0] += xv * w0.x; acc[1] += xv * w0.y;
        acc[2] += xv * w0.z; acc[3] += xv * w0.w;
        acc[4] += xv * w1.x; acc[5] += xv * w1.y;
        acc[6] += xv * w1.z; acc[7] += xv * w1.w;
    }
#pragma unroll
    for (int off = 32; off > 0; off >>= 1) {
#pragma unroll
        for (int e = 0; e < 8; ++e) acc[e] += __shfl_xor(acc[e], off);
    }

    float lg[8];
    float mx = -1e30f;
#pragma unroll
    for (int e = 0; e < 8; ++e) { lg[e] = acc[e] + bg[e]; mx = fmaxf(mx, lg[e]); }
    float sum = 0.f;
#pragma unroll
    for (int e = 0; e < 8; ++e) { lg[e] = expf(lg[e] - mx); sum += lg[e]; }
    float inv = 1.f / sum;

    float s1 = -1.f, s2 = -1.f; int i1 = 0, i2 = 0;
#pragma unroll
    for (int e = 0; e < 8; ++e) {
        float g = lg[e] * inv;
        if (g > s1)      { s2 = s1; i2 = i1; s1 = g; i1 = e; }
        else if (g > s2) { s2 = g;  i2 = e; }
    }
    if (lane == 0) {
        s12[token * 2]     = s1;
        s12[token * 2 + 1] = s2;
        if (token == 0) { eidx[0] = i1; eidx[1] = i2; }
    }
}

// ------------------------------- x -> bf16, slab order (staging image) ----
__global__ __launch_bounds__(256) void xconv_kernel(
    const float* __restrict__ x, unsigned short* __restrict__ xb) {
    const int mt = blockIdx.x >> 6;
    const int kt = blockIdx.x & 63;
    const int t  = threadIdx.x;
    const float* src = x + ((size_t)(mt * 256 + t)) * D_IN + kt * 32;
    unsigned short* slab = xb + ((size_t)(mt * 64 + kt)) * 8192;
#pragma unroll
    for (int ks = 0; ks < 4; ++ks) {
        float4 a = *(const float4*)(src + ks * 8);
        float4 b = *(const float4*)(src + ks * 8 + 4);
        u16x8 v;
        v[0] = f2bf(a.x); v[1] = f2bf(a.y); v[2] = f2bf(a.z); v[3] = f2bf(a.w);
        v[4] = f2bf(b.x); v[5] = f2bf(b.y); v[6] = f2bf(b.z); v[7] = f2bf(b.w);
        *(u16x8*)(slab + (ks * 256 + t) * 8) = v;
    }
}

// --------------------- W[e0],W[e1] -> bf16 slab order (transposed) --------
__global__ void wconv_kernel(const float* __restrict__ W,
                             const int* __restrict__ eidx,
                             unsigned short* __restrict__ wbT) {
    __shared__ float tile[64][65];
    const int be  = blockIdx.z;
    const int e   = eidx[be];
    const int k0  = blockIdx.y * 64;
    const int n0  = blockIdx.x * 64;
    const int bx  = n0 >> 7;
    const int cl0 = n0 & 127;
    const int kt0 = k0 >> 5;
    const float* src = W + (size_t)e * D_IN * D_HID;
    const int t = threadIdx.x;

#pragma unroll
    for (int p = 0; p < 4; ++p) {
        int row = p * 16 + (t >> 4);
        int col = (t & 15) * 4;
        const float* s = src + (size_t)(k0 + row) * D_HID + n0 + col;
        tile[row][col]     = s[0];
        tile[row][col + 1] = s[1];
        tile[row][col + 2] = s[2];
        tile[row][col + 3] = s[3];
    }
    __syncthreads();

    const int g   = (t >> 5) * 8;
    const int ktl = t >> 7;
    const int ks  = (t >> 5) & 3;
#pragma unroll
    for (int p = 0; p < 2; ++p) {
        int n = p * 32 + (t & 31);
        u16x8 v;
#pragma unroll
        for (int j = 0; j < 8; ++j) v[j] = f2bf(tile[g + j][n]);
        unsigned short* dst = wbT + ((size_t)(bx * 64 + kt0 + ktl)) * 8192 +
                              ((size_t)(ks * 256 + be * 128 + cl0 + n)) * 8;
        *(u16x8*)dst = v;
    }
}

// ------------------------------------------------------------------ GEMM --
// R6 geometry (256 rows x 128 cols x 2 experts, 8 waves, BK=32) but B is
// loaded DIRECTLY global->VGPR (L2-resident via XCD swizzle), register
// double-buffered one tile ahead. LDS carries only A: 4 buffers x 16 KB.
// LDS pipe drops from ~1500 to ~800 cyc/tile -> MFMA (1242) becomes the
// critical pipe. Mixed-vm fence chain (in-order retirement): steady
// vmcnt(12) retires A(t+1) (younger = B(t)4+A(t+2)2+B(t+1)4+A(t+3)2 = 12);
// B-register deps are compiler-tracked.
#define GLD16(gp, lp)                                                        \
    __builtin_amdgcn_global_load_lds(                                        \
        (const __attribute__((address_space(1))) void*)(gp),                 \
        (__attribute__((address_space(3))) void*)(lp), 16, 0, 0)

#define LDSV(SLOT) (*(const bf16x8*)&lds[(SLOT) * 8])

#define STAGE_A(SB, KT)                                                      \
    do {                                                                     \
        GLD16(gA0 + (size_t)(KT) * 8192,        &lds[((SB) * 1024 + t512) * 8]); \
        GLD16(gA0 + (size_t)(KT) * 8192 + 4096, &lds[((SB) * 1024 + 512 + t512) * 8]); \
    } while (0)

// TILE: read A frags (buf RB); load B(BT) -> BN; stage A(STGT); vmcnt;
// 32 MFMA (a x BC); barrier.
#define TILE(RB, STGT, DOSTG, BT, DOB, BC, BN, VMSTR, DOBAR)                 \
    do {                                                                     \
        bf16x8 a[8];                                                         \
        _Pragma("unroll")                                                    \
        for (int mi = 0; mi < 8; ++mi)                                       \
            a[mi] = LDSV((RB) * 1024 + abase + mi * 16);                     \
        if (DOB) {                                                           \
            const unsigned short* bp = gBfrag + (size_t)(BT) * 8192;         \
            _Pragma("unroll")                                                \
            for (int ni = 0; ni < 4; ++ni)                                   \
                BN[ni] = *(const bf16x8*)(bp + ni * 128);                    \
        }                                                                    \
        if (DOSTG) STAGE_A((STGT) & 3, STGT);                                \
        if (VMSTR[0]) asm volatile(VMSTR ::: "memory");                      \
        __builtin_amdgcn_s_setprio(1);                                       \
        _Pragma("unroll")                                                    \
        for (int mi = 0; mi < 8; ++mi)                                       \
            _Pragma("unroll")                                                \
            for (int ni = 0; ni < 4; ++ni)                                   \
                acc[mi][ni] = __builtin_amdgcn_mfma_f32_16x16x32_bf16(       \
                    a[mi], BC[ni], acc[mi][ni], 0, 0, 0);                    \
        __builtin_amdgcn_s_setprio(0);                                       \
        if (DOBAR) __builtin_amdgcn_s_barrier();                             \
    } while (0)

#define VM12 "s_waitcnt vmcnt(12)"

__global__ __launch_bounds__(512, 2) void moe_gemm_kernel(
    const unsigned short* __restrict__ xb,   // slab order [mt64][kt64][1024]
    const unsigned short* __restrict__ wbT,  // slab order [bx16][kt64][1024]
    const float* __restrict__ b_exp,         // [8][D_HID]
    const int* __restrict__ eidx,
    const float* __restrict__ s12,           // [N_TOK][2]
    float* __restrict__ out) {
    // A: 4 buffers x 1024 granules x 16B = 64 KiB; epilogue reuses 128 KiB
    __shared__ __align__(16) short lds[8192 * 8];

    const int t512 = threadIdx.x;
    const int lane = t512 & 63;
    const int w    = t512 >> 6;
    const int wm   = w >> 2;
    const int wn   = w & 3;

    // XCD swizzle: each XCD owns a bx pair (B slabs 2 MB -> L2-resident)
    const int bid = blockIdx.x;
    const int xcd = bid & 7;
    const int jb  = bid >> 3;
    const int bx  = xcd * 2 + (jb & 1);
    const int by  = jb >> 1;
    const int mbase = by * 256;
    const int nbase = bx * 128;

    const unsigned short* gA0 = xb + ((size_t)by * 64) * 8192 + t512 * 8;
    // per-lane B fragment source: slot = ks*256 + wn*64 + (lane&15) [+ni*16]
    const unsigned short* gBfrag =
        wbT + ((size_t)bx * 64) * 8192 +
        ((size_t)((lane >> 4) * 256 + wn * 64 + (lane & 15))) * 8;

    const int abase = (lane >> 4) * 256 + wm * 128 + (lane & 15);

    f32x4 acc[8][4];
#pragma unroll
    for (int mi = 0; mi < 8; ++mi)
#pragma unroll
        for (int ni = 0; ni < 4; ++ni) acc[mi][ni] = (f32x4){0.f, 0.f, 0.f, 0.f};

    bf16x8 b0[4], b1[4];

    // prologue: stage A tiles 0,1,2 (6 vm ops); load B(0) (4 vm ops).
    STAGE_A(0, 0);
    STAGE_A(1, 1);
    STAGE_A(2, 2);
#pragma unroll
    for (int ni = 0; ni < 4; ++ni)
        b0[ni] = *(const bf16x8*)(gBfrag + ni * 128);
    // A(0) retired when <=8 younger remain (A1 2, A2 2, B0 4)
    asm volatile("s_waitcnt vmcnt(8)" ::: "memory");
    __builtin_amdgcn_s_barrier();

    for (int t = 0; t < 56; t += 4) {
        TILE(0, t + 3, 1, t + 1, 1, b0, b1, VM12, 1);
        TILE(1, t + 4, 1, t + 2, 1, b1, b0, VM12, 1);
        TILE(2, t + 5, 1, t + 3, 1, b0, b1, VM12, 1);
        TILE(3, t + 6, 1, t + 4, 1, b1, b0, VM12, 1);
    }
    TILE(0, 59, 1, 57, 1, b0, b1, VM12, 1);   // tile 56
    TILE(1, 60, 1, 58, 1, b1, b0, VM12, 1);   // tile 57
    TILE(2, 61, 1, 59, 1, b0, b1, VM12, 1);   // tile 58
    TILE(3, 62, 1, 60, 1, b1, b0, VM12, 1);   // tile 59
    TILE(0, 63, 1, 61, 1, b0, b1, VM12, 1);   // tile 60
    TILE(1, 0, 0, 62, 1, b1, b0, "s_waitcnt vmcnt(10)", 1);  // tile 61
    TILE(2, 0, 0, 63, 1, b0, b1, "s_waitcnt vmcnt(8)", 1);   // tile 62
    TILE(3, 0, 0, 0, 0, b1, b0, "", 0);                      // tile 63

    // -------- epilogue: combine experts through LDS (f32) --------
    __syncthreads();
    float* fl = (float*)lds;
    if (wn >= 2) {
        float* reg = fl + (wm * 2 + (wn - 2)) * 8192;   // [128][64]
#pragma unroll
        for (int mi = 0; mi < 8; ++mi)
#pragma unroll
            for (int ni = 0; ni < 4; ++ni)
#pragma unroll
                for (int j = 0; j < 4; ++j) {
                    int row_l = mi * 16 + ((lane >> 4) << 2) + j;
                    int col_l = ni * 16 + (lane & 15);
                    reg[row_l * 64 + col_l] = acc[mi][ni][j];
                }
    }
    __syncthreads();
    if (wn < 2) {
        const float* reg = fl + (wm * 2 + wn) * 8192;
        const int e0 = eidx[0], e1 = eidx[1];
        const float* bb0 = b_exp + (size_t)e0 * D_HID;
        const float* bb1 = b_exp + (size_t)e1 * D_HID;
        const float2* s12v = (const float2*)s12;
        int   cc[4];
        float b0c[4], b1c[4];
#pragma unroll
        for (int ni = 0; ni < 4; ++ni) {
            cc[ni]  = nbase + wn * 64 + ni * 16 + (lane & 15);
            b0c[ni] = bb0[cc[ni]];
            b1c[ni] = bb1[cc[ni]];
        }
#pragma unroll
        for (int mi = 0; mi < 8; ++mi)
#pragma unroll
            for (int j = 0; j < 4; ++j) {
                int row_l = mi * 16 + ((lane >> 4) << 2) + j;
                int r = mbase + wm * 128 + row_l;
                float2 s = s12v[r];
#pragma unroll
                for (int ni = 0; ni < 4; ++ni) {
                    float y1 = reg[row_l * 64 + ni * 16 + (lane & 15)];
                    out[(size_t)r * D_HID + cc[ni]] =
                        s.x * (acc[mi][ni][j] + b0c[ni]) + s.y * (y1 + b1c[ni]);
                }
            }
    }
}

// ---------------------------------------------------------------- launch --
extern "C" void kernel_launch(void* const* d_in, const int* in_sizes, int n_in,
                              void* d_out, int out_size, void* d_ws, size_t ws_size,
                              hipStream_t stream) {
    const float* x         = (const float*)d_in[0];
    const float* W_experts = (const float*)d_in[1];
    const float* b_experts = (const float*)d_in[2];
    const float* W_gate    = (const float*)d_in[3];
    const float* b_gate    = (const float*)d_in[4];
    float* out = (float*)d_out;

    char* ws = (char*)d_ws;
    float* s12  = (float*)ws;                                        // 128 KiB
    int*   eidx = (int*)(ws + 131072);
    unsigned short* xb  = (unsigned short*)(ws + 262144);            // 64 MiB
    unsigned short* wbT = (unsigned short*)(ws + 262144 + 67108864); // 16 MiB

    gate_kernel<<<N_TOK / 4, 256, 0, stream>>>(x, W_gate, b_gate, s12, eidx);
    xconv_kernel<<<4096, 256, 0, stream>>>(x, xb);
    wconv_kernel<<<dim3(32, 32, 2), 256, 0, stream>>>(W_experts, eidx, wbT);
    moe_gemm_kernel<<<1024, 512, 0, stream>>>(xb, wbT, b_experts, eidx, s12, out);
}

// Round 12
// 316.818 us; speedup vs baseline: 1.1021x; 1.1021x over previous
//
#include <hip/hip_runtime.h>
#include <hip/hip_bf16.h>
#include <stdint.h>

#define N_TOK 16384
#define D_IN  2048
#define D_HID 2048

typedef __attribute__((ext_vector_type(8)))  short bf16x8;
typedef __attribute__((ext_vector_type(16))) float f32x16;
typedef __attribute__((ext_vector_type(8)))  unsigned short u16x8;

__device__ __forceinline__ unsigned short f2bf(float f) {
    unsigned int u = __float_as_uint(f);
    u = (u + 0x7FFFu + ((u >> 16) & 1u)) >> 16;
    return (unsigned short)u;
}

// ---------------- xconv2: x -> bf16 slabs + gate partials (fused) ---------
// Block (mt,kt): thread t = token row. Reads 128 B contiguous of x, writes
// 4 slab granules (1 KB/wave contiguous), and accumulates the 8-expert
// partial dot over its 32-k slice. W_gate reads are wave-uniform ->
// compiler emits s_load (SGPR operands, no LDS). Partials go to d_out
// scratch [mt][kt][256 tok][8] (32 B/thread contiguous; GEMM overwrites
// d_out afterwards every call - no cross-call state).
__global__ __launch_bounds__(256) void xconv2_kernel(
    const float* __restrict__ x, const float* __restrict__ Wg,
    unsigned short* __restrict__ xb, float* __restrict__ part) {
    const int mt = blockIdx.x >> 6;
    const int kt = blockIdx.x & 63;
    const int t  = threadIdx.x;
    const float* src = x + ((size_t)(mt * 256 + t)) * D_IN + kt * 32;
    unsigned short* slab = xb + ((size_t)(mt * 64 + kt)) * 8192;
    const float* wg = Wg + kt * 32 * 8;   // wave-uniform base

    float p[8];
#pragma unroll
    for (int e = 0; e < 8; ++e) p[e] = 0.f;

#pragma unroll
    for (int ks = 0; ks < 4; ++ks) {
        float4 a = *(const float4*)(src + ks * 8);
        float4 b = *(const float4*)(src + ks * 8 + 4);
        float xv[8] = {a.x, a.y, a.z, a.w, b.x, b.y, b.z, b.w};
        u16x8 v;
#pragma unroll
        for (int j = 0; j < 8; ++j) v[j] = f2bf(xv[j]);
        *(u16x8*)(slab + (ks * 256 + t) * 8) = v;
#pragma unroll
        for (int j = 0; j < 8; ++j)
#pragma unroll
            for (int e = 0; e < 8; ++e)
                p[e] += xv[j] * wg[(ks * 8 + j) * 8 + e];
    }
    float* dst = part + (((size_t)(mt * 64 + kt)) * 256 + t) * 8;
#pragma unroll
    for (int e = 0; e < 8; ++e) dst[e] = p[e];
}

// ---------------- gatefin: reduce partials -> softmax -> top-2 ------------
__global__ __launch_bounds__(256) void gatefin_kernel(
    const float* __restrict__ part, const float* __restrict__ bg,
    float* __restrict__ s12, int* __restrict__ eidx) {
    const int mt = blockIdx.x;
    const int t  = threadIdx.x;
    float l8[8];
#pragma unroll
    for (int e = 0; e < 8; ++e) l8[e] = 0.f;
    for (int kt = 0; kt < 64; ++kt) {
        const float* pp = part + (((size_t)(mt * 64 + kt)) * 256 + t) * 8;
        float4 a = *(const float4*)pp;
        float4 b = *(const float4*)(pp + 4);
        l8[0] += a.x; l8[1] += a.y; l8[2] += a.z; l8[3] += a.w;
        l8[4] += b.x; l8[5] += b.y; l8[6] += b.z; l8[7] += b.w;
    }
    float mx = -1e30f;
#pragma unroll
    for (int e = 0; e < 8; ++e) { l8[e] += bg[e]; mx = fmaxf(mx, l8[e]); }
    float sum = 0.f;
#pragma unroll
    for (int e = 0; e < 8; ++e) { l8[e] = expf(l8[e] - mx); sum += l8[e]; }
    float inv = 1.f / sum;
    float s1 = -1.f, s2 = -1.f; int i1 = 0, i2 = 0;
#pragma unroll
    for (int e = 0; e < 8; ++e) {
        float g = l8[e] * inv;
        if (g > s1)      { s2 = s1; i2 = i1; s1 = g; i1 = e; }
        else if (g > s2) { s2 = g;  i2 = e; }
    }
    const int token = mt * 256 + t;
    s12[token * 2]     = s1;
    s12[token * 2 + 1] = s2;
    if (token == 0) { eidx[0] = i1; eidx[1] = i2; }
}

// --------------------- W[e0],W[e1] -> bf16 slab order (transposed) --------
__global__ void wconv_kernel(const float* __restrict__ W,
                             const int* __restrict__ eidx,
                             unsigned short* __restrict__ wbT) {
    __shared__ float tile[64][65];
    const int be  = blockIdx.z;
    const int e   = eidx[be];
    const int k0  = blockIdx.y * 64;
    const int n0  = blockIdx.x * 64;
    const int bx  = n0 >> 7;
    const int cl0 = n0 & 127;
    const int kt0 = k0 >> 5;
    const float* src = W + (size_t)e * D_IN * D_HID;
    const int t = threadIdx.x;

#pragma unroll
    for (int p = 0; p < 4; ++p) {
        int row = p * 16 + (t >> 4);
        int col = (t & 15) * 4;
        const float* s = src + (size_t)(k0 + row) * D_HID + n0 + col;
        tile[row][col]     = s[0];
        tile[row][col + 1] = s[1];
        tile[row][col + 2] = s[2];
        tile[row][col + 3] = s[3];
    }
    __syncthreads();

    const int g   = (t >> 5) * 8;
    const int ktl = t >> 7;
    const int ks  = (t >> 5) & 3;
#pragma unroll
    for (int p = 0; p < 2; ++p) {
        int n = p * 32 + (t & 31);
        u16x8 v;
#pragma unroll
        for (int j = 0; j < 8; ++j) v[j] = f2bf(tile[g + j][n]);
        unsigned short* dst = wbT + ((size_t)(bx * 64 + kt0 + ktl)) * 8192 +
                              ((size_t)(ks * 256 + be * 128 + cl0 + n)) * 8;
        *(u16x8*)dst = v;
    }
}

// ------------------------------------------------------------------ GEMM --
// R6's proven schedule (232 us: two-barrier TILE, 12 ds_read b128/tile,
// vmcnt 6/4/0, 4 buffers depth-3, slab staging, setprio, XCD swizzle) with
// 32x32x16 MFMA frags (R4-verified mapping): half the MFMA instructions at
// the 2495-TF rate -> MFMA floor 318k -> 268k cyc/CU.
#define GLD16(gp, lp)                                                        \
    __builtin_amdgcn_global_load_lds(                                        \
        (const __attribute__((address_space(1))) void*)(gp),                 \
        (__attribute__((address_space(3))) void*)(lp), 16, 0, 0)

#define LDSV(SLOT) (*(const bf16x8*)&lds[(SLOT) * 8])

#define STAGE_A(SBAS, KT)                                                    \
    do {                                                                     \
        GLD16(gA0 + (size_t)(KT) * 8192,        &lds[((SBAS) + t512) * 8]);  \
        GLD16(gA0 + (size_t)(KT) * 8192 + 4096, &lds[((SBAS) + 512 + t512) * 8]); \
    } while (0)
#define STAGE_B(SBAS, KT)                                                    \
    do {                                                                     \
        GLD16(gB0 + (size_t)(KT) * 8192,        &lds[((SBAS) + 1024 + t512) * 8]); \
        GLD16(gB0 + (size_t)(KT) * 8192 + 4096, &lds[((SBAS) + 1536 + t512) * 8]); \
    } while (0)

#define MFC(KK)                                                              \
    _Pragma("unroll")                                                        \
    for (int mi = 0; mi < 4; ++mi)                                           \
        _Pragma("unroll")                                                    \
        for (int ni = 0; ni < 2; ++ni)                                       \
            acc[mi][ni] = __builtin_amdgcn_mfma_f32_32x32x16_bf16(           \
                af[KK][mi], bf[KK][ni], acc[mi][ni], 0, 0, 0);

#define TILE(RB, SB, KT, DO_STAGE, VMSTR)                                    \
    do {                                                                     \
        const int rbas = (RB) * 2048;                                        \
        bf16x8 af[2][4], bf[2][2];                                           \
        _Pragma("unroll")                                                    \
        for (int kk = 0; kk < 2; ++kk) {                                     \
            _Pragma("unroll")                                                \
            for (int ni = 0; ni < 2; ++ni)                                   \
                bf[kk][ni] = LDSV(rbas + 1024 + kk * 512 + bbase + ni * 32); \
            _Pragma("unroll")                                                \
            for (int mi = 0; mi < 4; ++mi)                                   \
                af[kk][mi] = LDSV(rbas + kk * 512 + abase + mi * 32);        \
        }                                                                    \
        __builtin_amdgcn_s_barrier();                                        \
        if (DO_STAGE) STAGE_A((SB) * 2048, KT);                              \
        __builtin_amdgcn_s_setprio(1);                                       \
        MFC(0)                                                               \
        __builtin_amdgcn_s_setprio(0);                                       \
        asm volatile(VMSTR ::: "memory");                                    \
        __builtin_amdgcn_s_barrier();                                        \
        if (DO_STAGE) STAGE_B((SB) * 2048, KT);                              \
        __builtin_amdgcn_s_setprio(1);                                       \
        MFC(1)                                                               \
        __builtin_amdgcn_s_setprio(0);                                       \
    } while (0)

__global__ __launch_bounds__(512, 2) void moe_gemm_kernel(
    const unsigned short* __restrict__ xb,   // slab order [mt64][kt64][1024]
    const unsigned short* __restrict__ wbT,  // slab order [bx16][kt64][1024]
    const float* __restrict__ b_exp,         // [8][D_HID]
    const int* __restrict__ eidx,
    const float* __restrict__ s12,           // [N_TOK][2]
    float* __restrict__ out) {
    // 4 buffers x (A 1024 + B 1024 granules) x 16B = 128 KiB
    __shared__ __align__(16) short lds[4 * 2048 * 8];

    const int t512 = threadIdx.x;
    const int lane = t512 & 63;
    const int w    = t512 >> 6;
    const int wm   = w >> 2;      // row half
    const int wn   = w & 3;       // 0..1 expert0 strips, 2..3 expert1
    const int lsk  = lane >> 5;   // k-half of fragment
    const int lr   = lane & 31;

    // XCD swizzle: each XCD owns a bx pair (B slabs 2 MB -> L2-resident)
    const int bid = blockIdx.x;
    const int xcd = bid & 7;
    const int jb  = bid >> 3;
    const int bx  = xcd * 2 + (jb & 1);
    const int by  = jb >> 1;
    const int mbase = by * 256;
    const int nbase = bx * 128;

    const unsigned short* gA0 = xb  + ((size_t)by * 64) * 8192 + t512 * 8;
    const unsigned short* gB0 = wbT + ((size_t)bx * 64) * 8192 + t512 * 8;

    // frag bases (granule units): slot = (kk*2+lsk)*256 + row
    const int abase = lsk * 256 + wm * 128 + lr;
    const int bbase = lsk * 256 + wn * 64 + lr;

    f32x16 acc[4][2];
#pragma unroll
    for (int mi = 0; mi < 4; ++mi)
#pragma unroll
        for (int ni = 0; ni < 2; ++ni)
#pragma unroll
            for (int r = 0; r < 16; ++r) acc[mi][ni][r] = 0.f;

    // prologue: stage tiles 0,1,2 (12 loads); vmcnt(8) retires tile 0.
    STAGE_A(0, 0);    STAGE_B(0, 0);
    STAGE_A(2048, 1); STAGE_B(2048, 1);
    STAGE_A(4096, 2); STAGE_B(4096, 2);
    asm volatile("s_waitcnt vmcnt(8)" ::: "memory");
    __builtin_amdgcn_s_barrier();

#pragma unroll 4
    for (int t = 0; t < 61; ++t) {
        TILE(t & 3, (t + 3) & 3, t + 3, 1, "s_waitcnt vmcnt(6)");
    }
    TILE(1, 0, 0, 0, "s_waitcnt vmcnt(4)");
    TILE(2, 0, 0, 0, "s_waitcnt vmcnt(0)");
    TILE(3, 0, 0, 0, "s_waitcnt vmcnt(0)");

    // -------- epilogue: combine experts through LDS (f32) --------
    // 32x32 C/D layout (R4-verified): row=(r&3)+8*(r>>2)+4*lsk, col=lr.
    __syncthreads();
    float* fl = (float*)lds;
    if (wn >= 2) {
        float* reg = fl + (wm * 2 + (wn - 2)) * 8192;   // [128][64]
#pragma unroll
        for (int mi = 0; mi < 4; ++mi)
#pragma unroll
            for (int ni = 0; ni < 2; ++ni)
#pragma unroll
                for (int r = 0; r < 16; ++r) {
                    int row_l = mi * 32 + (r & 3) + 8 * (r >> 2) + 4 * lsk;
                    reg[row_l * 64 + ni * 32 + lr] = acc[mi][ni][r];
                }
    }
    __syncthreads();
    if (wn < 2) {
        const float* reg = fl + (wm * 2 + wn) * 8192;
        const int e0 = eidx[0], e1 = eidx[1];
        const float* bb0 = b_exp + (size_t)e0 * D_HID;
        const float* bb1 = b_exp + (size_t)e1 * D_HID;
        const float2* s12v = (const float2*)s12;
        int   cc[2];
        float b0c[2], b1c[2];
#pragma unroll
        for (int ni = 0; ni < 2; ++ni) {
            cc[ni]  = nbase + wn * 64 + ni * 32 + lr;
            b0c[ni] = bb0[cc[ni]];
            b1c[ni] = bb1[cc[ni]];
        }
#pragma unroll
        for (int mi = 0; mi < 4; ++mi)
#pragma unroll
            for (int r = 0; r < 16; ++r) {
                int row_l = mi * 32 + (r & 3) + 8 * (r >> 2) + 4 * lsk;
                int rg = mbase + wm * 128 + row_l;
                float2 s = s12v[rg];
#pragma unroll
                for (int ni = 0; ni < 2; ++ni) {
                    float y1 = reg[row_l * 64 + ni * 32 + lr];
                    out[(size_t)rg * D_HID + cc[ni]] =
                        s.x * (acc[mi][ni][r] + b0c[ni]) + s.y * (y1 + b1c[ni]);
                }
            }
    }
}

// ---------------------------------------------------------------- launch --
extern "C" void kernel_launch(void* const* d_in, const int* in_sizes, int n_in,
                              void* d_out, int out_size, void* d_ws, size_t ws_size,
                              hipStream_t stream) {
    const float* x         = (const float*)d_in[0];
    const float* W_experts = (const float*)d_in[1];
    const float* b_experts = (const float*)d_in[2];
    const float* W_gate    = (const float*)d_in[3];
    const float* b_gate    = (const float*)d_in[4];
    float* out = (float*)d_out;

    char* ws = (char*)d_ws;
    float* s12  = (float*)ws;                                        // 128 KiB
    int*   eidx = (int*)(ws + 131072);
    unsigned short* xb  = (unsigned short*)(ws + 262144);            // 64 MiB
    unsigned short* wbT = (unsigned short*)(ws + 262144 + 67108864); // 16 MiB
    float* part = out;   // 33.5 MB gate partials in d_out scratch (GEMM
                         // fully overwrites out afterwards, every call)

    xconv2_kernel<<<4096, 256, 0, stream>>>(x, W_gate, xb, part);
    gatefin_kernel<<<64, 256, 0, stream>>>(part, b_gate, s12, eidx);
    wconv_kernel<<<dim3(32, 32, 2), 256, 0, stream>>>(W_experts, eidx, wbT);
    moe_gemm_kernel<<<1024, 512, 0, stream>>>(xb, wbT, b_experts, eidx, s12, out);
}

// Round 13
// 296.879 us; speedup vs baseline: 1.1761x; 1.0672x over previous
//
#include <hip/hip_runtime.h>
#include <hip/hip_bf16.h>
#include <stdint.h>

#define N_TOK 16384
#define D_IN  2048
#define D_HID 2048

typedef __attribute__((ext_vector_type(8))) short  bf16x8;
typedef __attribute__((ext_vector_type(4))) float  f32x4;
typedef __attribute__((ext_vector_type(8))) unsigned short u16x8;

__device__ __forceinline__ unsigned short f2bf(float f) {
    unsigned int u = __float_as_uint(f);
    u = (u + 0x7FFFu + ((u >> 16) & 1u)) >> 16;
    return (unsigned short)u;
}

// ---------------- xconv2: x -> bf16 slabs + gate partials (fused) ---------
// Block (mt,kt): thread t = token row. Reads 128 B contiguous of x, writes
// 4 slab granules (1 KB/wave contiguous), and accumulates the 8-expert
// partial dot over its 32-k slice. W_gate reads are wave-uniform ->
// s_load path. Partials go to d_out scratch [mt][kt][256 tok][8]
// (32 B/thread contiguous; GEMM fully overwrites d_out afterwards).
__global__ __launch_bounds__(256) void xconv2_kernel(
    const float* __restrict__ x, const float* __restrict__ Wg,
    unsigned short* __restrict__ xb, float* __restrict__ part) {
    const int mt = blockIdx.x >> 6;
    const int kt = blockIdx.x & 63;
    const int t  = threadIdx.x;
    const float* src = x + ((size_t)(mt * 256 + t)) * D_IN + kt * 32;
    unsigned short* slab = xb + ((size_t)(mt * 64 + kt)) * 8192;
    const float* wg = Wg + kt * 32 * 8;   // wave-uniform base

    float p[8];
#pragma unroll
    for (int e = 0; e < 8; ++e) p[e] = 0.f;

#pragma unroll
    for (int ks = 0; ks < 4; ++ks) {
        float4 a = *(const float4*)(src + ks * 8);
        float4 b = *(const float4*)(src + ks * 8 + 4);
        float xv[8] = {a.x, a.y, a.z, a.w, b.x, b.y, b.z, b.w};
        u16x8 v;
#pragma unroll
        for (int j = 0; j < 8; ++j) v[j] = f2bf(xv[j]);
        *(u16x8*)(slab + (ks * 256 + t) * 8) = v;
#pragma unroll
        for (int j = 0; j < 8; ++j)
#pragma unroll
            for (int e = 0; e < 8; ++e)
                p[e] += xv[j] * wg[(ks * 8 + j) * 8 + e];
    }
    float* dst = part + (((size_t)(mt * 64 + kt)) * 256 + t) * 8;
#pragma unroll
    for (int e = 0; e < 8; ++e) dst[e] = p[e];
}

// ---------------- gatefin: reduce partials -> softmax -> top-2 ------------
__global__ __launch_bounds__(256) void gatefin_kernel(
    const float* __restrict__ part, const float* __restrict__ bg,
    float* __restrict__ s12, int* __restrict__ eidx) {
    const int mt = blockIdx.x;
    const int t  = threadIdx.x;
    float l8[8];
#pragma unroll
    for (int e = 0; e < 8; ++e) l8[e] = 0.f;
    for (int kt = 0; kt < 64; ++kt) {
        const float* pp = part + (((size_t)(mt * 64 + kt)) * 256 + t) * 8;
        float4 a = *(const float4*)pp;
        float4 b = *(const float4*)(pp + 4);
        l8[0] += a.x; l8[1] += a.y; l8[2] += a.z; l8[3] += a.w;
        l8[4] += b.x; l8[5] += b.y; l8[6] += b.z; l8[7] += b.w;
    }
    float mx = -1e30f;
#pragma unroll
    for (int e = 0; e < 8; ++e) { l8[e] += bg[e]; mx = fmaxf(mx, l8[e]); }
    float sum = 0.f;
#pragma unroll
    for (int e = 0; e < 8; ++e) { l8[e] = expf(l8[e] - mx); sum += l8[e]; }
    float inv = 1.f / sum;
    float s1 = -1.f, s2 = -1.f; int i1 = 0, i2 = 0;
#pragma unroll
    for (int e = 0; e < 8; ++e) {
        float g = l8[e] * inv;
        if (g > s1)      { s2 = s1; i2 = i1; s1 = g; i1 = e; }
        else if (g > s2) { s2 = g;  i2 = e; }
    }
    const int token = mt * 256 + t;
    s12[token * 2]     = s1;
    s12[token * 2 + 1] = s2;
    if (token == 0) { eidx[0] = i1; eidx[1] = i2; }
}

// --------------------- W[e0],W[e1] -> bf16 slab order (transposed) --------
__global__ void wconv_kernel(const float* __restrict__ W,
                             const int* __restrict__ eidx,
                             unsigned short* __restrict__ wbT) {
    __shared__ float tile[64][65];
    const int be  = blockIdx.z;
    const int e   = eidx[be];
    const int k0  = blockIdx.y * 64;
    const int n0  = blockIdx.x * 64;
    const int bx  = n0 >> 7;
    const int cl0 = n0 & 127;
    const int kt0 = k0 >> 5;
    const float* src = W + (size_t)e * D_IN * D_HID;
    const int t = threadIdx.x;

#pragma unroll
    for (int p = 0; p < 4; ++p) {
        int row = p * 16 + (t >> 4);
        int col = (t & 15) * 4;
        const float* s = src + (size_t)(k0 + row) * D_HID + n0 + col;
        tile[row][col]     = s[0];
        tile[row][col + 1] = s[1];
        tile[row][col + 2] = s[2];
        tile[row][col + 3] = s[3];
    }
    __syncthreads();

    const int g   = (t >> 5) * 8;
    const int ktl = t >> 7;
    const int ks  = (t >> 5) & 3;
#pragma unroll
    for (int p = 0; p < 2; ++p) {
        int n = p * 32 + (t & 31);
        u16x8 v;
#pragma unroll
        for (int j = 0; j < 8; ++j) v[j] = f2bf(tile[g + j][n]);
        unsigned short* dst = wbT + ((size_t)(bx * 64 + kt0 + ktl)) * 8192 +
                              ((size_t)(ks * 256 + be * 128 + cl0 + n)) * 8;
        *(u16x8*)dst = v;
    }
}

// ------------------------------------------------------------------ GEMM --
// Byte-for-byte the R6 232-us kernel: 256 rows x (128 cols x 2 experts),
// BK=32, 16x16x32 MFMA, 4 LDS buffers depth-3, contiguous slab staging,
// two-barrier TILE, vmcnt 6/4/0, setprio, XCD swizzle (B L2-resident).
#define GLD16(gp, lp)                                                        \
    __builtin_amdgcn_global_load_lds(                                        \
        (const __attribute__((address_space(1))) void*)(gp),                 \
        (__attribute__((address_space(3))) void*)(lp), 16, 0, 0)

#define LDSV(SLOT) (*(const bf16x8*)&lds[(SLOT) * 8])

#define STAGE_A(SBAS, KT)                                                    \
    do {                                                                     \
        GLD16(gA0 + (size_t)(KT) * 8192,        &lds[((SBAS) + t512) * 8]);  \
        GLD16(gA0 + (size_t)(KT) * 8192 + 4096, &lds[((SBAS) + 512 + t512) * 8]); \
    } while (0)
#define STAGE_B(SBAS, KT)                                                    \
    do {                                                                     \
        GLD16(gB0 + (size_t)(KT) * 8192,        &lds[((SBAS) + 1024 + t512) * 8]); \
        GLD16(gB0 + (size_t)(KT) * 8192 + 4096, &lds[((SBAS) + 1536 + t512) * 8]); \
    } while (0)

#define MF(MI, AV)                                                                              \
    acc[MI][0] = __builtin_amdgcn_mfma_f32_16x16x32_bf16(AV, bf0, acc[MI][0], 0, 0, 0);         \
    acc[MI][1] = __builtin_amdgcn_mfma_f32_16x16x32_bf16(AV, bf1, acc[MI][1], 0, 0, 0);         \
    acc[MI][2] = __builtin_amdgcn_mfma_f32_16x16x32_bf16(AV, bf2, acc[MI][2], 0, 0, 0);         \
    acc[MI][3] = __builtin_amdgcn_mfma_f32_16x16x32_bf16(AV, bf3, acc[MI][3], 0, 0, 0);

#define TILE(RB, SB, KT, DO_STAGE, VMSTR)                                    \
    do {                                                                     \
        const int rbas  = (RB) * 2048;                                       \
        const int abase = rbas + aks + arow;                                 \
        const int bbase = rbas + 1024 + aks + brow;                          \
        bf16x8 bf0 = LDSV(bbase), bf1 = LDSV(bbase + 16),                    \
               bf2 = LDSV(bbase + 32), bf3 = LDSV(bbase + 48);               \
        bf16x8 a0 = LDSV(abase), a1 = LDSV(abase + 16),                      \
               a2 = LDSV(abase + 32), a3 = LDSV(abase + 48);                 \
        bf16x8 a4 = LDSV(abase + 64), a5 = LDSV(abase + 80),                 \
               a6 = LDSV(abase + 96), a7 = LDSV(abase + 112);                \
        __builtin_amdgcn_s_barrier();                                        \
        if (DO_STAGE) STAGE_A((SB) * 2048, KT);                              \
        __builtin_amdgcn_s_setprio(1);                                       \
        MF(0, a0) MF(1, a1) MF(2, a2) MF(3, a3)                              \
        __builtin_amdgcn_s_setprio(0);                                       \
        asm volatile(VMSTR ::: "memory");                                    \
        __builtin_amdgcn_s_barrier();                                        \
        if (DO_STAGE) STAGE_B((SB) * 2048, KT);                              \
        __builtin_amdgcn_s_setprio(1);                                       \
        MF(4, a4) MF(5, a5) MF(6, a6) MF(7, a7)                              \
        __builtin_amdgcn_s_setprio(0);                                       \
    } while (0)

__global__ __launch_bounds__(512, 2) void moe_gemm_kernel(
    const unsigned short* __restrict__ xb,   // slab order [mt64][kt64][1024]
    const unsigned short* __restrict__ wbT,  // slab order [bx16][kt64][1024]
    const float* __restrict__ b_exp,         // [8][D_HID]
    const int* __restrict__ eidx,
    const float* __restrict__ s12,           // [N_TOK][2]
    float* __restrict__ out) {
    __shared__ __align__(16) short lds[4 * 2048 * 8];  // 128 KiB

    const int t512 = threadIdx.x;
    const int lane = t512 & 63;
    const int w    = t512 >> 6;
    const int wm   = w >> 2;
    const int wn   = w & 3;

    const int bid = blockIdx.x;
    const int xcd = bid & 7;
    const int jb  = bid >> 3;
    const int bx  = xcd * 2 + (jb & 1);
    const int by  = jb >> 1;
    const int mbase = by * 256;
    const int nbase = bx * 128;

    const unsigned short* gA0 = xb  + ((size_t)by * 64) * 8192 + t512 * 8;
    const unsigned short* gB0 = wbT + ((size_t)bx * 64) * 8192 + t512 * 8;

    const int aks  = (lane >> 4) * 256;
    const int arow = wm * 128 + (lane & 15);
    const int brow = wn * 64 + (lane & 15);

    f32x4 acc[8][4];
#pragma unroll
    for (int mi = 0; mi < 8; ++mi)
#pragma unroll
        for (int ni = 0; ni < 4; ++ni) acc[mi][ni] = (f32x4){0.f, 0.f, 0.f, 0.f};

    STAGE_A(0, 0);    STAGE_B(0, 0);
    STAGE_A(2048, 1); STAGE_B(2048, 1);
    STAGE_A(4096, 2); STAGE_B(4096, 2);
    asm volatile("s_waitcnt vmcnt(8)" ::: "memory");
    __builtin_amdgcn_s_barrier();

#pragma unroll 4
    for (int t = 0; t < 61; ++t) {
        TILE(t & 3, (t + 3) & 3, t + 3, 1, "s_waitcnt vmcnt(6)");
    }
    TILE(1, 0, 0, 0, "s_waitcnt vmcnt(4)");
    TILE(2, 0, 0, 0, "s_waitcnt vmcnt(0)");
    TILE(3, 0, 0, 0, "s_waitcnt vmcnt(0)");

    // -------- epilogue: combine experts through LDS (f32) --------
    __syncthreads();
    float* fl = (float*)lds;
    if (wn >= 2) {
        float* reg = fl + (wm * 2 + (wn - 2)) * 8192;   // [128][64]
#pragma unroll
        for (int mi = 0; mi < 8; ++mi)
#pragma unroll
            for (int ni = 0; ni < 4; ++ni)
#pragma unroll
                for (int j = 0; j < 4; ++j) {
                    int row_l = mi * 16 + ((lane >> 4) << 2) + j;
                    int col_l = ni * 16 + (lane & 15);
                    reg[row_l * 64 + col_l] = acc[mi][ni][j];
                }
    }
    __syncthreads();
    if (wn < 2) {
        const float* reg = fl + (wm * 2 + wn) * 8192;
        const int e0 = eidx[0], e1 = eidx[1];
        const float* bb0 = b_exp + (size_t)e0 * D_HID;
        const float* bb1 = b_exp + (size_t)e1 * D_HID;
        const float2* s12v = (const float2*)s12;
        int   cc[4];
        float b0c[4], b1c[4];
#pragma unroll
        for (int ni = 0; ni < 4; ++ni) {
            cc[ni]  = nbase + wn * 64 + ni * 16 + (lane & 15);
            b0c[ni] = bb0[cc[ni]];
            b1c[ni] = bb1[cc[ni]];
        }
#pragma unroll
        for (int mi = 0; mi < 8; ++mi)
#pragma unroll
            for (int j = 0; j < 4; ++j) {
                int row_l = mi * 16 + ((lane >> 4) << 2) + j;
                int r = mbase + wm * 128 + row_l;
                float2 s = s12v[r];
#pragma unroll
                for (int ni = 0; ni < 4; ++ni) {
                    float y1 = reg[row_l * 64 + ni * 16 + (lane & 15)];
                    out[(size_t)r * D_HID + cc[ni]] =
                        s.x * (acc[mi][ni][j] + b0c[ni]) + s.y * (y1 + b1c[ni]);
                }
            }
    }
}

// ---------------------------------------------------------------- launch --
extern "C" void kernel_launch(void* const* d_in, const int* in_sizes, int n_in,
                              void* d_out, int out_size, void* d_ws, size_t ws_size,
                              hipStream_t stream) {
    const float* x         = (const float*)d_in[0];
    const float* W_experts = (const float*)d_in[1];
    const float* b_experts = (const float*)d_in[2];
    const float* W_gate    = (const float*)d_in[3];
    const float* b_gate    = (const float*)d_in[4];
    float* out = (float*)d_out;

    char* ws = (char*)d_ws;
    float* s12  = (float*)ws;                                        // 128 KiB
    int*   eidx = (int*)(ws + 131072);
    unsigned short* xb  = (unsigned short*)(ws + 262144);            // 64 MiB
    unsigned short* wbT = (unsigned short*)(ws + 262144 + 67108864); // 16 MiB
    float* part = out;   // 33.5 MB gate partials in d_out scratch (GEMM
                         // fully overwrites out afterwards, every call)

    xconv2_kernel<<<4096, 256, 0, stream>>>(x, W_gate, xb, part);
    gatefin_kernel<<<64, 256, 0, stream>>>(part, b_gate, s12, eidx);
    wconv_kernel<<<dim3(32, 32, 2), 256, 0, stream>>>(W_experts, eidx, wbT);
    moe_gemm_kernel<<<1024, 512, 0, stream>>>(xb, wbT, b_experts, eidx, s12, out);
}

// Round 14
// 295.878 us; speedup vs baseline: 1.1801x; 1.0034x over previous
//
#include <hip/hip_runtime.h>
#include <hip/hip_bf16.h>
#include <stdint.h>

#define N_TOK 16384
#define D_IN  2048
#define D_HID 2048

typedef __attribute__((ext_vector_type(8))) short  bf16x8;
typedef __attribute__((ext_vector_type(4))) float  f32x4;
typedef __attribute__((ext_vector_type(8))) unsigned short u16x8;

__device__ __forceinline__ unsigned short f2bf(float f) {
    unsigned int u = __float_as_uint(f);
    u = (u + 0x7FFFu + ((u >> 16) & 1u)) >> 16;
    return (unsigned short)u;
}

// ---------------- xconv2: x -> bf16 slabs + gate partials (fused) ---------
__global__ __launch_bounds__(256) void xconv2_kernel(
    const float* __restrict__ x, const float* __restrict__ Wg,
    unsigned short* __restrict__ xb, float* __restrict__ part) {
    const int mt = blockIdx.x >> 6;
    const int kt = blockIdx.x & 63;
    const int t  = threadIdx.x;
    const float* src = x + ((size_t)(mt * 256 + t)) * D_IN + kt * 32;
    unsigned short* slab = xb + ((size_t)(mt * 64 + kt)) * 8192;
    const float* wg = Wg + kt * 32 * 8;   // wave-uniform base -> s_load path

    float p[8];
#pragma unroll
    for (int e = 0; e < 8; ++e) p[e] = 0.f;

#pragma unroll
    for (int ks = 0; ks < 4; ++ks) {
        float4 a = *(const float4*)(src + ks * 8);
        float4 b = *(const float4*)(src + ks * 8 + 4);
        float xv[8] = {a.x, a.y, a.z, a.w, b.x, b.y, b.z, b.w};
        u16x8 v;
#pragma unroll
        for (int j = 0; j < 8; ++j) v[j] = f2bf(xv[j]);
        *(u16x8*)(slab + (ks * 256 + t) * 8) = v;
#pragma unroll
        for (int j = 0; j < 8; ++j)
#pragma unroll
            for (int e = 0; e < 8; ++e)
                p[e] += xv[j] * wg[(ks * 8 + j) * 8 + e];
    }
    float* dst = part + (((size_t)(mt * 64 + kt)) * 256 + t) * 8;
#pragma unroll
    for (int e = 0; e < 8; ++e) dst[e] = p[e];
}

// ---------------- gatefin: reduce partials -> softmax -> top-2 ------------
__global__ __launch_bounds__(256) void gatefin_kernel(
    const float* __restrict__ part, const float* __restrict__ bg,
    float* __restrict__ s12, int* __restrict__ eidx) {
    const int mt = blockIdx.x;
    const int t  = threadIdx.x;
    float l8[8];
#pragma unroll
    for (int e = 0; e < 8; ++e) l8[e] = 0.f;
    for (int kt = 0; kt < 64; ++kt) {
        const float* pp = part + (((size_t)(mt * 64 + kt)) * 256 + t) * 8;
        float4 a = *(const float4*)pp;
        float4 b = *(const float4*)(pp + 4);
        l8[0] += a.x; l8[1] += a.y; l8[2] += a.z; l8[3] += a.w;
        l8[4] += b.x; l8[5] += b.y; l8[6] += b.z; l8[7] += b.w;
    }
    float mx = -1e30f;
#pragma unroll
    for (int e = 0; e < 8; ++e) { l8[e] += bg[e]; mx = fmaxf(mx, l8[e]); }
    float sum = 0.f;
#pragma unroll
    for (int e = 0; e < 8; ++e) { l8[e] = expf(l8[e] - mx); sum += l8[e]; }
    float inv = 1.f / sum;
    float s1 = -1.f, s2 = -1.f; int i1 = 0, i2 = 0;
#pragma unroll
    for (int e = 0; e < 8; ++e) {
        float g = l8[e] * inv;
        if (g > s1)      { s2 = s1; i2 = i1; s1 = g; i1 = e; }
        else if (g > s2) { s2 = g;  i2 = e; }
    }
    const int token = mt * 256 + t;
    s12[token * 2]     = s1;
    s12[token * 2 + 1] = s2;
    if (token == 0) { eidx[0] = i1; eidx[1] = i2; }
}

// --------------------- W[e0],W[e1] -> bf16 slab order (transposed) --------
__global__ void wconv_kernel(const float* __restrict__ W,
                             const int* __restrict__ eidx,
                             unsigned short* __restrict__ wbT) {
    __shared__ float tile[64][65];
    const int be  = blockIdx.z;
    const int e   = eidx[be];
    const int k0  = blockIdx.y * 64;
    const int n0  = blockIdx.x * 64;
    const int bx  = n0 >> 7;
    const int cl0 = n0 & 127;
    const int kt0 = k0 >> 5;
    const float* src = W + (size_t)e * D_IN * D_HID;
    const int t = threadIdx.x;

#pragma unroll
    for (int p = 0; p < 4; ++p) {
        int row = p * 16 + (t >> 4);
        int col = (t & 15) * 4;
        const float* s = src + (size_t)(k0 + row) * D_HID + n0 + col;
        tile[row][col]     = s[0];
        tile[row][col + 1] = s[1];
        tile[row][col + 2] = s[2];
        tile[row][col + 3] = s[3];
    }
    __syncthreads();

    const int g   = (t >> 5) * 8;
    const int ktl = t >> 7;
    const int ks  = (t >> 5) & 3;
#pragma unroll
    for (int p = 0; p < 2; ++p) {
        int n = p * 32 + (t & 31);
        u16x8 v;
#pragma unroll
        for (int j = 0; j < 8; ++j) v[j] = f2bf(tile[g + j][n]);
        unsigned short* dst = wbT + ((size_t)(bx * 64 + kt0 + ktl)) * 8192 +
                              ((size_t)(ks * 256 + be * 128 + cl0 + n)) * 8;
        *(u16x8*)dst = v;
    }
}

// ------------------------------------------------------------------ GEMM --
// R6 data movement with ONE barrier per K-tile: {12 ds_read | 4 gload_lds |
// vmcnt(4) | bar | 32 MFMA}. Hazards: (H1) reads of buf t&3 end pre-bar(t);
// overwriting stages (tile t+4 @ TILE(t+1)) issue post-bar(t). (H2) tile
// t+2's loads retired by vmcnt(4) pre-bar(t), fenced by bar(t), read two
// tiles later. 64 fewer chip-wide barriers than R13; uninterrupted 32-MFMA
// setprio cluster; vmcnt waits on >=2-tile-old loads (~zero stall).
#define GLD16(gp, lp)                                                        \
    __builtin_amdgcn_global_load_lds(                                        \
        (const __attribute__((address_space(1))) void*)(gp),                 \
        (__attribute__((address_space(3))) void*)(lp), 16, 0, 0)

#define LDSV(SLOT) (*(const bf16x8*)&lds[(SLOT) * 8])

#define STAGE_A(SBAS, KT)                                                    \
    do {                                                                     \
        GLD16(gA0 + (size_t)(KT) * 8192,        &lds[((SBAS) + t512) * 8]);  \
        GLD16(gA0 + (size_t)(KT) * 8192 + 4096, &lds[((SBAS) + 512 + t512) * 8]); \
    } while (0)
#define STAGE_B(SBAS, KT)                                                    \
    do {                                                                     \
        GLD16(gB0 + (size_t)(KT) * 8192,        &lds[((SBAS) + 1024 + t512) * 8]); \
        GLD16(gB0 + (size_t)(KT) * 8192 + 4096, &lds[((SBAS) + 1536 + t512) * 8]); \
    } while (0)

#define MF(MI, AV)                                                                              \
    acc[MI][0] = __builtin_amdgcn_mfma_f32_16x16x32_bf16(AV, bf0, acc[MI][0], 0, 0, 0);         \
    acc[MI][1] = __builtin_amdgcn_mfma_f32_16x16x32_bf16(AV, bf1, acc[MI][1], 0, 0, 0);         \
    acc[MI][2] = __builtin_amdgcn_mfma_f32_16x16x32_bf16(AV, bf2, acc[MI][2], 0, 0, 0);         \
    acc[MI][3] = __builtin_amdgcn_mfma_f32_16x16x32_bf16(AV, bf3, acc[MI][3], 0, 0, 0);

#define TILE(RB, SB, KT, DO_STAGE, VMSTR)                                    \
    do {                                                                     \
        const int rbas  = (RB) * 2048;                                       \
        const int abase = rbas + aks + arow;                                 \
        const int bbase = rbas + 1024 + aks + brow;                          \
        bf16x8 bf0 = LDSV(bbase), bf1 = LDSV(bbase + 16),                    \
               bf2 = LDSV(bbase + 32), bf3 = LDSV(bbase + 48);               \
        bf16x8 a0 = LDSV(abase), a1 = LDSV(abase + 16),                      \
               a2 = LDSV(abase + 32), a3 = LDSV(abase + 48);                 \
        bf16x8 a4 = LDSV(abase + 64), a5 = LDSV(abase + 80),                 \
               a6 = LDSV(abase + 96), a7 = LDSV(abase + 112);                \
        if (DO_STAGE) { STAGE_A((SB) * 2048, KT); STAGE_B((SB) * 2048, KT); }\
        if (VMSTR[0]) asm volatile(VMSTR ::: "memory");                      \
        __builtin_amdgcn_s_barrier();                                        \
        __builtin_amdgcn_s_setprio(1);                                       \
        MF(0, a0) MF(1, a1) MF(2, a2) MF(3, a3)                              \
        MF(4, a4) MF(5, a5) MF(6, a6) MF(7, a7)                              \
        __builtin_amdgcn_s_setprio(0);                                       \
    } while (0)

__global__ __launch_bounds__(512, 2) void moe_gemm_kernel(
    const unsigned short* __restrict__ xb,   // slab order [mt64][kt64][1024]
    const unsigned short* __restrict__ wbT,  // slab order [bx16][kt64][1024]
    const float* __restrict__ b_exp,         // [8][D_HID]
    const int* __restrict__ eidx,
    const float* __restrict__ s12,           // [N_TOK][2]
    float* __restrict__ out) {
    __shared__ __align__(16) short lds[4 * 2048 * 8];  // 128 KiB

    const int t512 = threadIdx.x;
    const int lane = t512 & 63;
    const int w    = t512 >> 6;
    const int wm   = w >> 2;
    const int wn   = w & 3;

    const int bid = blockIdx.x;
    const int xcd = bid & 7;
    const int jb  = bid >> 3;
    const int bx  = xcd * 2 + (jb & 1);
    const int by  = jb >> 1;
    const int mbase = by * 256;
    const int nbase = bx * 128;

    const unsigned short* gA0 = xb  + ((size_t)by * 64) * 8192 + t512 * 8;
    const unsigned short* gB0 = wbT + ((size_t)bx * 64) * 8192 + t512 * 8;

    const int aks  = (lane >> 4) * 256;
    const int arow = wm * 128 + (lane & 15);
    const int brow = wn * 64 + (lane & 15);

    f32x4 acc[8][4];
#pragma unroll
    for (int mi = 0; mi < 8; ++mi)
#pragma unroll
        for (int ni = 0; ni < 4; ++ni) acc[mi][ni] = (f32x4){0.f, 0.f, 0.f, 0.f};

    // prologue: stage tiles 0,1,2 (12 loads); vmcnt(4) retires tiles 0,1.
    STAGE_A(0, 0);    STAGE_B(0, 0);
    STAGE_A(2048, 1); STAGE_B(2048, 1);
    STAGE_A(4096, 2); STAGE_B(4096, 2);
    asm volatile("s_waitcnt vmcnt(4)" ::: "memory");
    __builtin_amdgcn_s_barrier();

#pragma unroll 4
    for (int t = 0; t < 61; ++t) {
        TILE(t & 3, (t + 3) & 3, t + 3, 1, "s_waitcnt vmcnt(4)");
    }
    TILE(1, 0, 0, 0, "s_waitcnt vmcnt(4)");   // tile 61 (no wait in practice)
    TILE(2, 0, 0, 0, "s_waitcnt vmcnt(0)");   // tile 62: retire tile 63
    TILE(3, 0, 0, 0, "");                     // tile 63

    // -------- epilogue: combine experts through LDS (f32) --------
    __syncthreads();
    float* fl = (float*)lds;
    if (wn >= 2) {
        float* reg = fl + (wm * 2 + (wn - 2)) * 8192;   // [128][64]
#pragma unroll
        for (int mi = 0; mi < 8; ++mi)
#pragma unroll
            for (int ni = 0; ni < 4; ++ni)
#pragma unroll
                for (int j = 0; j < 4; ++j) {
                    int row_l = mi * 16 + ((lane >> 4) << 2) + j;
                    int col_l = ni * 16 + (lane & 15);
                    reg[row_l * 64 + col_l] = acc[mi][ni][j];
                }
    }
    __syncthreads();
    if (wn < 2) {
        const float* reg = fl + (wm * 2 + wn) * 8192;
        const int e0 = eidx[0], e1 = eidx[1];
        const float* bb0 = b_exp + (size_t)e0 * D_HID;
        const float* bb1 = b_exp + (size_t)e1 * D_HID;
        const float2* s12v = (const float2*)s12;
        int   cc[4];
        float b0c[4], b1c[4];
#pragma unroll
        for (int ni = 0; ni < 4; ++ni) {
            cc[ni]  = nbase + wn * 64 + ni * 16 + (lane & 15);
            b0c[ni] = bb0[cc[ni]];
            b1c[ni] = bb1[cc[ni]];
        }
#pragma unroll
        for (int mi = 0; mi < 8; ++mi)
#pragma unroll
            for (int j = 0; j < 4; ++j) {
                int row_l = mi * 16 + ((lane >> 4) << 2) + j;
                int r = mbase + wm * 128 + row_l;
                float2 s = s12v[r];
#pragma unroll
                for (int ni = 0; ni < 4; ++ni) {
                    float y1 = reg[row_l * 64 + ni * 16 + (lane & 15)];
                    out[(size_t)r * D_HID + cc[ni]] =
                        s.x * (acc[mi][ni][j] + b0c[ni]) + s.y * (y1 + b1c[ni]);
                }
            }
    }
}

// ---------------------------------------------------------------- launch --
extern "C" void kernel_launch(void* const* d_in, const int* in_sizes, int n_in,
                              void* d_out, int out_size, void* d_ws, size_t ws_size,
                              hipStream_t stream) {
    const float* x         = (const float*)d_in[0];
    const float* W_experts = (const float*)d_in[1];
    const float* b_experts = (const float*)d_in[2];
    const float* W_gate    = (const float*)d_in[3];
    const float* b_gate    = (const float*)d_in[4];
    float* out = (float*)d_out;

    char* ws = (char*)d_ws;
    float* s12  = (float*)ws;                                        // 128 KiB
    int*   eidx = (int*)(ws + 131072);
    unsigned short* xb  = (unsigned short*)(ws + 262144);            // 64 MiB
    unsigned short* wbT = (unsigned short*)(ws + 262144 + 67108864); // 16 MiB
    float* part = out;   // gate partials in d_out scratch (GEMM overwrites)

    xconv2_kernel<<<4096, 256, 0, stream>>>(x, W_gate, xb, part);
    gatefin_kernel<<<64, 256, 0, stream>>>(part, b_gate, s12, eidx);
    wconv_kernel<<<dim3(32, 32, 2), 256, 0, stream>>>(W_experts, eidx, wbT);
    moe_gemm_kernel<<<1024, 512, 0, stream>>>(xb, wbT, b_experts, eidx, s12, out);
}

// Round 15
// 292.785 us; speedup vs baseline: 1.1926x; 1.0106x over previous
//
#include <hip/hip_runtime.h>
#include <hip/hip_bf16.h>
#include <stdint.h>

#define N_TOK 16384
#define D_IN  2048
#define D_HID 2048

typedef __attribute__((ext_vector_type(8))) short  bf16x8;
typedef __attribute__((ext_vector_type(4))) float  f32x4;
typedef __attribute__((ext_vector_type(8))) unsigned short u16x8;

__device__ __forceinline__ unsigned short f2bf(float f) {
    unsigned int u = __float_as_uint(f);
    u = (u + 0x7FFFu + ((u >> 16) & 1u)) >> 16;
    return (unsigned short)u;
}

// ---------------- xconv2: x -> bf16 slabs + gate partials (fused) ---------
__global__ __launch_bounds__(256) void xconv2_kernel(
    const float* __restrict__ x, const float* __restrict__ Wg,
    unsigned short* __restrict__ xb, float* __restrict__ part) {
    const int mt = blockIdx.x >> 6;
    const int kt = blockIdx.x & 63;
    const int t  = threadIdx.x;
    const float* src = x + ((size_t)(mt * 256 + t)) * D_IN + kt * 32;
    unsigned short* slab = xb + ((size_t)(mt * 64 + kt)) * 8192;
    const float* wg = Wg + kt * 32 * 8;   // wave-uniform base -> s_load path

    float p[8];
#pragma unroll
    for (int e = 0; e < 8; ++e) p[e] = 0.f;

#pragma unroll
    for (int ks = 0; ks < 4; ++ks) {
        float4 a = *(const float4*)(src + ks * 8);
        float4 b = *(const float4*)(src + ks * 8 + 4);
        float xv[8] = {a.x, a.y, a.z, a.w, b.x, b.y, b.z, b.w};
        u16x8 v;
#pragma unroll
        for (int j = 0; j < 8; ++j) v[j] = f2bf(xv[j]);
        *(u16x8*)(slab + (ks * 256 + t) * 8) = v;
#pragma unroll
        for (int j = 0; j < 8; ++j)
#pragma unroll
            for (int e = 0; e < 8; ++e)
                p[e] += xv[j] * wg[(ks * 8 + j) * 8 + e];
    }
    float* dst = part + (((size_t)(mt * 64 + kt)) * 256 + t) * 8;
#pragma unroll
    for (int e = 0; e < 8; ++e) dst[e] = p[e];
}

// ---------------- gatefin: reduce partials -> softmax -> top-2 ------------
// 256 blocks (full-chip BW): block = 64 tokens of quarter-mt q; thread
// (s = t>>6, tok = t&63) sums kt-slice [s*16, s*16+16); LDS reduce of the
// 4 slices; slice-0 threads finish softmax + top-2.
__global__ __launch_bounds__(256) void gatefin_kernel(
    const float* __restrict__ part, const float* __restrict__ bg,
    float* __restrict__ s12, int* __restrict__ eidx) {
    __shared__ float red[4][64][8];
    const int mt  = blockIdx.x >> 2;
    const int q   = blockIdx.x & 3;
    const int tok = threadIdx.x & 63;
    const int s   = threadIdx.x >> 6;

    float l8[8];
#pragma unroll
    for (int e = 0; e < 8; ++e) l8[e] = 0.f;
#pragma unroll 4
    for (int k = 0; k < 16; ++k) {
        const int kt = s * 16 + k;
        const float* pp =
            part + (((size_t)(mt * 64 + kt)) * 256 + q * 64 + tok) * 8;
        float4 a = *(const float4*)pp;
        float4 b = *(const float4*)(pp + 4);
        l8[0] += a.x; l8[1] += a.y; l8[2] += a.z; l8[3] += a.w;
        l8[4] += b.x; l8[5] += b.y; l8[6] += b.z; l8[7] += b.w;
    }
#pragma unroll
    for (int e = 0; e < 8; ++e) red[s][tok][e] = l8[e];
    __syncthreads();
    if (s == 0) {
        float mx = -1e30f;
#pragma unroll
        for (int e = 0; e < 8; ++e) {
            l8[e] = red[0][tok][e] + red[1][tok][e] + red[2][tok][e] +
                    red[3][tok][e] + bg[e];
            mx = fmaxf(mx, l8[e]);
        }
        float sum = 0.f;
#pragma unroll
        for (int e = 0; e < 8; ++e) { l8[e] = expf(l8[e] - mx); sum += l8[e]; }
        float inv = 1.f / sum;
        float s1 = -1.f, s2 = -1.f; int i1 = 0, i2 = 0;
#pragma unroll
        for (int e = 0; e < 8; ++e) {
            float g = l8[e] * inv;
            if (g > s1)      { s2 = s1; i2 = i1; s1 = g; i1 = e; }
            else if (g > s2) { s2 = g;  i2 = e; }
        }
        const int token = mt * 256 + q * 64 + tok;
        s12[token * 2]     = s1;
        s12[token * 2 + 1] = s2;
        if (token == 0) { eidx[0] = i1; eidx[1] = i2; }
    }
}

// --------------------- W[e0],W[e1] -> bf16 slab order (transposed) --------
__global__ void wconv_kernel(const float* __restrict__ W,
                             const int* __restrict__ eidx,
                             unsigned short* __restrict__ wbT) {
    __shared__ float tile[64][65];
    const int be  = blockIdx.z;
    const int e   = eidx[be];
    const int k0  = blockIdx.y * 64;
    const int n0  = blockIdx.x * 64;
    const int bx  = n0 >> 7;
    const int cl0 = n0 & 127;
    const int kt0 = k0 >> 5;
    const float* src = W + (size_t)e * D_IN * D_HID;
    const int t = threadIdx.x;

#pragma unroll
    for (int p = 0; p < 4; ++p) {
        int row = p * 16 + (t >> 4);
        int col = (t & 15) * 4;
        const float* s = src + (size_t)(k0 + row) * D_HID + n0 + col;
        tile[row][col]     = s[0];
        tile[row][col + 1] = s[1];
        tile[row][col + 2] = s[2];
        tile[row][col + 3] = s[3];
    }
    __syncthreads();

    const int g   = (t >> 5) * 8;
    const int ktl = t >> 7;
    const int ks  = (t >> 5) & 3;
#pragma unroll
    for (int p = 0; p < 2; ++p) {
        int n = p * 32 + (t & 31);
        u16x8 v;
#pragma unroll
        for (int j = 0; j < 8; ++j) v[j] = f2bf(tile[g + j][n]);
        unsigned short* dst = wbT + ((size_t)(bx * 64 + kt0 + ktl)) * 8192 +
                              ((size_t)(ks * 256 + be * 128 + cl0 + n)) * 8;
        *(u16x8*)dst = v;
    }
}

// ------------------------------------------------------------------ GEMM --
// R14's best state (221.5 us): one barrier per K-tile {12 ds_read |
// 4 gload_lds | vmcnt(4) | bar | 32 MFMA}, 4 buffers depth-3 slab staging,
// 16x16x32 MFMA, setprio, XCD swizzle (B L2-resident). Hazards H1/H2
// derived in R14 comment.
#define GLD16(gp, lp)                                                        \
    __builtin_amdgcn_global_load_lds(                                        \
        (const __attribute__((address_space(1))) void*)(gp),                 \
        (__attribute__((address_space(3))) void*)(lp), 16, 0, 0)

#define LDSV(SLOT) (*(const bf16x8*)&lds[(SLOT) * 8])

#define STAGE_A(SBAS, KT)                                                    \
    do {                                                                     \
        GLD16(gA0 + (size_t)(KT) * 8192,        &lds[((SBAS) + t512) * 8]);  \
        GLD16(gA0 + (size_t)(KT) * 8192 + 4096, &lds[((SBAS) + 512 + t512) * 8]); \
    } while (0)
#define STAGE_B(SBAS, KT)                                                    \
    do {                                                                     \
        GLD16(gB0 + (size_t)(KT) * 8192,        &lds[((SBAS) + 1024 + t512) * 8]); \
        GLD16(gB0 + (size_t)(KT) * 8192 + 4096, &lds[((SBAS) + 1536 + t512) * 8]); \
    } while (0)

#define MF(MI, AV)                                                                              \
    acc[MI][0] = __builtin_amdgcn_mfma_f32_16x16x32_bf16(AV, bf0, acc[MI][0], 0, 0, 0);         \
    acc[MI][1] = __builtin_amdgcn_mfma_f32_16x16x32_bf16(AV, bf1, acc[MI][1], 0, 0, 0);         \
    acc[MI][2] = __builtin_amdgcn_mfma_f32_16x16x32_bf16(AV, bf2, acc[MI][2], 0, 0, 0);         \
    acc[MI][3] = __builtin_amdgcn_mfma_f32_16x16x32_bf16(AV, bf3, acc[MI][3], 0, 0, 0);

#define TILE(RB, SB, KT, DO_STAGE, VMSTR)                                    \
    do {                                                                     \
        const int rbas  = (RB) * 2048;                                       \
        const int abase = rbas + aks + arow;                                 \
        const int bbase = rbas + 1024 + aks + brow;                          \
        bf16x8 bf0 = LDSV(bbase), bf1 = LDSV(bbase + 16),                    \
               bf2 = LDSV(bbase + 32), bf3 = LDSV(bbase + 48);               \
        bf16x8 a0 = LDSV(abase), a1 = LDSV(abase + 16),                      \
               a2 = LDSV(abase + 32), a3 = LDSV(abase + 48);                 \
        bf16x8 a4 = LDSV(abase + 64), a5 = LDSV(abase + 80),                 \
               a6 = LDSV(abase + 96), a7 = LDSV(abase + 112);                \
        if (DO_STAGE) { STAGE_A((SB) * 2048, KT); STAGE_B((SB) * 2048, KT); }\
        if (VMSTR[0]) asm volatile(VMSTR ::: "memory");                      \
        __builtin_amdgcn_s_barrier();                                        \
        __builtin_amdgcn_s_setprio(1);                                       \
        MF(0, a0) MF(1, a1) MF(2, a2) MF(3, a3)                              \
        MF(4, a4) MF(5, a5) MF(6, a6) MF(7, a7)                              \
        __builtin_amdgcn_s_setprio(0);                                       \
    } while (0)

__global__ __launch_bounds__(512, 2) void moe_gemm_kernel(
    const unsigned short* __restrict__ xb,   // slab order [mt64][kt64][1024]
    const unsigned short* __restrict__ wbT,  // slab order [bx16][kt64][1024]
    const float* __restrict__ b_exp,         // [8][D_HID]
    const int* __restrict__ eidx,
    const float* __restrict__ s12,           // [N_TOK][2]
    float* __restrict__ out) {
    __shared__ __align__(16) short lds[4 * 2048 * 8];  // 128 KiB

    const int t512 = threadIdx.x;
    const int lane = t512 & 63;
    const int w    = t512 >> 6;
    const int wm   = w >> 2;
    const int wn   = w & 3;

    const int bid = blockIdx.x;
    const int xcd = bid & 7;
    const int jb  = bid >> 3;
    const int bx  = xcd * 2 + (jb & 1);
    const int by  = jb >> 1;
    const int mbase = by * 256;
    const int nbase = bx * 128;

    const unsigned short* gA0 = xb  + ((size_t)by * 64) * 8192 + t512 * 8;
    const unsigned short* gB0 = wbT + ((size_t)bx * 64) * 8192 + t512 * 8;

    const int aks  = (lane >> 4) * 256;
    const int arow = wm * 128 + (lane & 15);
    const int brow = wn * 64 + (lane & 15);

    f32x4 acc[8][4];
#pragma unroll
    for (int mi = 0; mi < 8; ++mi)
#pragma unroll
        for (int ni = 0; ni < 4; ++ni) acc[mi][ni] = (f32x4){0.f, 0.f, 0.f, 0.f};

    STAGE_A(0, 0);    STAGE_B(0, 0);
    STAGE_A(2048, 1); STAGE_B(2048, 1);
    STAGE_A(4096, 2); STAGE_B(4096, 2);
    asm volatile("s_waitcnt vmcnt(4)" ::: "memory");
    __builtin_amdgcn_s_barrier();

#pragma unroll 4
    for (int t = 0; t < 61; ++t) {
        TILE(t & 3, (t + 3) & 3, t + 3, 1, "s_waitcnt vmcnt(4)");
    }
    TILE(1, 0, 0, 0, "s_waitcnt vmcnt(4)");   // tile 61 (no wait in practice)
    TILE(2, 0, 0, 0, "s_waitcnt vmcnt(0)");   // tile 62: retire tile 63
    TILE(3, 0, 0, 0, "");                     // tile 63

    // -------- epilogue: combine experts through LDS (f32) --------
    __syncthreads();
    float* fl = (float*)lds;
    if (wn >= 2) {
        float* reg = fl + (wm * 2 + (wn - 2)) * 8192;   // [128][64]
#pragma unroll
        for (int mi = 0; mi < 8; ++mi)
#pragma unroll
            for (int ni = 0; ni < 4; ++ni)
#pragma unroll
                for (int j = 0; j < 4; ++j) {
                    int row_l = mi * 16 + ((lane >> 4) << 2) + j;
                    int col_l = ni * 16 + (lane & 15);
                    reg[row_l * 64 + col_l] = acc[mi][ni][j];
                }
    }
    __syncthreads();
    if (wn < 2) {
        const float* reg = fl + (wm * 2 + wn) * 8192;
        const int e0 = eidx[0], e1 = eidx[1];
        const float* bb0 = b_exp + (size_t)e0 * D_HID;
        const float* bb1 = b_exp + (size_t)e1 * D_HID;
        const float2* s12v = (const float2*)s12;
        int   cc[4];
        float b0c[4], b1c[4];
#pragma unroll
        for (int ni = 0; ni < 4; ++ni) {
            cc[ni]  = nbase + wn * 64 + ni * 16 + (lane & 15);
            b0c[ni] = bb0[cc[ni]];
            b1c[ni] = bb1[cc[ni]];
        }
#pragma unroll
        for (int mi = 0; mi < 8; ++mi)
#pragma unroll
            for (int j = 0; j < 4; ++j) {
                int row_l = mi * 16 + ((lane >> 4) << 2) + j;
                int r = mbase + wm * 128 + row_l;
                float2 s = s12v[r];
#pragma unroll
                for (int ni = 0; ni < 4; ++ni) {
                    float y1 = reg[row_l * 64 + ni * 16 + (lane & 15)];
                    out[(size_t)r * D_HID + cc[ni]] =
                        s.x * (acc[mi][ni][j] + b0c[ni]) + s.y * (y1 + b1c[ni]);
                }
            }
    }
}

// ---------------------------------------------------------------- launch --
extern "C" void kernel_launch(void* const* d_in, const int* in_sizes, int n_in,
                              void* d_out, int out_size, void* d_ws, size_t ws_size,
                              hipStream_t stream) {
    const float* x         = (const float*)d_in[0];
    const float* W_experts = (const float*)d_in[1];
    const float* b_experts = (const float*)d_in[2];
    const float* W_gate    = (const float*)d_in[3];
    const float* b_gate    = (const float*)d_in[4];
    float* out = (float*)d_out;

    char* ws = (char*)d_ws;
    float* s12  = (float*)ws;                                        // 128 KiB
    int*   eidx = (int*)(ws + 131072);
    unsigned short* xb  = (unsigned short*)(ws + 262144);            // 64 MiB
    unsigned short* wbT = (unsigned short*)(ws + 262144 + 67108864); // 16 MiB
    float* part = out;   // gate partials in d_out scratch (GEMM overwrites)

    xconv2_kernel<<<4096, 256, 0, stream>>>(x, W_gate, xb, part);
    gatefin_kernel<<<256, 256, 0, stream>>>(part, b_gate, s12, eidx);
    wconv_kernel<<<dim3(32, 32, 2), 256, 0, stream>>>(W_experts, eidx, wbT);
    moe_gemm_kernel<<<1024, 512, 0, stream>>>(xb, wbT, b_experts, eidx, s12, out);
}

// Round 16
// 291.291 us; speedup vs baseline: 1.1987x; 1.0051x over previous
//
#include <hip/hip_runtime.h>
#include <hip/hip_bf16.h>
#include <stdint.h>

#define N_TOK 16384
#define D_IN  2048
#define D_HID 2048

typedef __attribute__((ext_vector_type(8))) short  bf16x8;
typedef __attribute__((ext_vector_type(4))) float  f32x4;
typedef __attribute__((ext_vector_type(8))) unsigned short u16x8;

__device__ __forceinline__ unsigned short f2bf(float f) {
    unsigned int u = __float_as_uint(f);
    u = (u + 0x7FFFu + ((u >> 16) & 1u)) >> 16;
    return (unsigned short)u;
}

// ---------------- xconv3: x -> bf16 slabs + gate partials (8 kt/block) ----
// Block (mt, g): thread t = token row; loops kt = g*8 .. g*8+7. Per kt:
// read 128 B line-dense x slice, write 4 slab granules (1 KB/wave
// contiguous), accumulate gate partial over 256 k in registers. ONE 32-B
// partial store per thread -> part shrinks 67 MB round-trip to 8.4 MB.
__global__ __launch_bounds__(256) void xconv3_kernel(
    const float* __restrict__ x, const float* __restrict__ Wg,
    unsigned short* __restrict__ xb, float* __restrict__ part) {
    const int mt = blockIdx.x >> 3;       // 64 token-tiles
    const int g  = blockIdx.x & 7;        // 8 kt-groups of 8
    const int t  = threadIdx.x;

    float p[8];
#pragma unroll
    for (int e = 0; e < 8; ++e) p[e] = 0.f;

#pragma unroll
    for (int q = 0; q < 8; ++q) {
        const int kt = g * 8 + q;
        const float* src = x + ((size_t)(mt * 256 + t)) * D_IN + kt * 32;
        unsigned short* slab = xb + ((size_t)(mt * 64 + kt)) * 8192;
        const float* wg = Wg + kt * 32 * 8;   // wave-uniform -> s_load path
#pragma unroll
        for (int ks = 0; ks < 4; ++ks) {
            float4 a = *(const float4*)(src + ks * 8);
            float4 b = *(const float4*)(src + ks * 8 + 4);
            float xv[8] = {a.x, a.y, a.z, a.w, b.x, b.y, b.z, b.w};
            u16x8 v;
#pragma unroll
            for (int j = 0; j < 8; ++j) v[j] = f2bf(xv[j]);
            *(u16x8*)(slab + (ks * 256 + t) * 8) = v;
#pragma unroll
            for (int j = 0; j < 8; ++j)
#pragma unroll
                for (int e = 0; e < 8; ++e)
                    p[e] += xv[j] * wg[(ks * 8 + j) * 8 + e];
        }
    }
    float* dst = part + (((size_t)(mt * 8 + g)) * 256 + t) * 8;
#pragma unroll
    for (int e = 0; e < 8; ++e) dst[e] = p[e];
}

// ---------------- gatefin: reduce 8 partials -> softmax -> top-2 ----------
// 256 blocks (mt, quarter q); thread (s = t>>6, tok = t&63) sums groups
// {2s, 2s+1}; LDS reduce; slice-0 finishes softmax + top-2.
__global__ __launch_bounds__(256) void gatefin_kernel(
    const float* __restrict__ part, const float* __restrict__ bg,
    float* __restrict__ s12, int* __restrict__ eidx) {
    __shared__ float red[4][64][8];
    const int mt  = blockIdx.x >> 2;
    const int q   = blockIdx.x & 3;
    const int tok = threadIdx.x & 63;
    const int s   = threadIdx.x >> 6;

    float l8[8];
#pragma unroll
    for (int e = 0; e < 8; ++e) l8[e] = 0.f;
#pragma unroll
    for (int gg = 0; gg < 2; ++gg) {
        const int gidx = s * 2 + gg;
        const float* pp =
            part + (((size_t)(mt * 8 + gidx)) * 256 + q * 64 + tok) * 8;
        float4 a = *(const float4*)pp;
        float4 b = *(const float4*)(pp + 4);
        l8[0] += a.x; l8[1] += a.y; l8[2] += a.z; l8[3] += a.w;
        l8[4] += b.x; l8[5] += b.y; l8[6] += b.z; l8[7] += b.w;
    }
#pragma unroll
    for (int e = 0; e < 8; ++e) red[s][tok][e] = l8[e];
    __syncthreads();
    if (s == 0) {
        float mx = -1e30f;
#pragma unroll
        for (int e = 0; e < 8; ++e) {
            l8[e] = red[0][tok][e] + red[1][tok][e] + red[2][tok][e] +
                    red[3][tok][e] + bg[e];
            mx = fmaxf(mx, l8[e]);
        }
        float sum = 0.f;
#pragma unroll
        for (int e = 0; e < 8; ++e) { l8[e] = expf(l8[e] - mx); sum += l8[e]; }
        float inv = 1.f / sum;
        float s1 = -1.f, s2 = -1.f; int i1 = 0, i2 = 0;
#pragma unroll
        for (int e = 0; e < 8; ++e) {
            float g = l8[e] * inv;
            if (g > s1)      { s2 = s1; i2 = i1; s1 = g; i1 = e; }
            else if (g > s2) { s2 = g;  i2 = e; }
        }
        const int token = mt * 256 + q * 64 + tok;
        s12[token * 2]     = s1;
        s12[token * 2 + 1] = s2;
        if (token == 0) { eidx[0] = i1; eidx[1] = i2; }
    }
}

// --------------------- W[e0],W[e1] -> bf16 slab order (transposed) --------
__global__ void wconv_kernel(const float* __restrict__ W,
                             const int* __restrict__ eidx,
                             unsigned short* __restrict__ wbT) {
    __shared__ float tile[64][65];
    const int be  = blockIdx.z;
    const int e   = eidx[be];
    const int k0  = blockIdx.y * 64;
    const int n0  = blockIdx.x * 64;
    const int bx  = n0 >> 7;
    const int cl0 = n0 & 127;
    const int kt0 = k0 >> 5;
    const float* src = W + (size_t)e * D_IN * D_HID;
    const int t = threadIdx.x;

#pragma unroll
    for (int p = 0; p < 4; ++p) {
        int row = p * 16 + (t >> 4);
        int col = (t & 15) * 4;
        const float* s = src + (size_t)(k0 + row) * D_HID + n0 + col;
        tile[row][col]     = s[0];
        tile[row][col + 1] = s[1];
        tile[row][col + 2] = s[2];
        tile[row][col + 3] = s[3];
    }
    __syncthreads();

    const int g   = (t >> 5) * 8;
    const int ktl = t >> 7;
    const int ks  = (t >> 5) & 3;
#pragma unroll
    for (int p = 0; p < 2; ++p) {
        int n = p * 32 + (t & 31);
        u16x8 v;
#pragma unroll
        for (int j = 0; j < 8; ++j) v[j] = f2bf(tile[g + j][n]);
        unsigned short* dst = wbT + ((size_t)(bx * 64 + kt0 + ktl)) * 8192 +
                              ((size_t)(ks * 256 + be * 128 + cl0 + n)) * 8;
        *(u16x8*)dst = v;
    }
}

// ------------------------------------------------------------------ GEMM --
// R14/R15 best state (221.5 us, byte-identical): one barrier per K-tile
// {12 ds_read | 4 gload_lds | vmcnt(4) | bar | 32 MFMA}, 4 buffers depth-3
// slab staging, 16x16x32 MFMA, setprio, XCD swizzle (B L2-resident).
#define GLD16(gp, lp)                                                        \
    __builtin_amdgcn_global_load_lds(                                        \
        (const __attribute__((address_space(1))) void*)(gp),                 \
        (__attribute__((address_space(3))) void*)(lp), 16, 0, 0)

#define LDSV(SLOT) (*(const bf16x8*)&lds[(SLOT) * 8])

#define STAGE_A(SBAS, KT)                                                    \
    do {                                                                     \
        GLD16(gA0 + (size_t)(KT) * 8192,        &lds[((SBAS) + t512) * 8]);  \
        GLD16(gA0 + (size_t)(KT) * 8192 + 4096, &lds[((SBAS) + 512 + t512) * 8]); \
    } while (0)
#define STAGE_B(SBAS, KT)                                                    \
    do {                                                                     \
        GLD16(gB0 + (size_t)(KT) * 8192,        &lds[((SBAS) + 1024 + t512) * 8]); \
        GLD16(gB0 + (size_t)(KT) * 8192 + 4096, &lds[((SBAS) + 1536 + t512) * 8]); \
    } while (0)

#define MF(MI, AV)                                                                              \
    acc[MI][0] = __builtin_amdgcn_mfma_f32_16x16x32_bf16(AV, bf0, acc[MI][0], 0, 0, 0);         \
    acc[MI][1] = __builtin_amdgcn_mfma_f32_16x16x32_bf16(AV, bf1, acc[MI][1], 0, 0, 0);         \
    acc[MI][2] = __builtin_amdgcn_mfma_f32_16x16x32_bf16(AV, bf2, acc[MI][2], 0, 0, 0);         \
    acc[MI][3] = __builtin_amdgcn_mfma_f32_16x16x32_bf16(AV, bf3, acc[MI][3], 0, 0, 0);

#define TILE(RB, SB, KT, DO_STAGE, VMSTR)                                    \
    do {                                                                     \
        const int rbas  = (RB) * 2048;                                       \
        const int abase = rbas + aks + arow;                                 \
        const int bbase = rbas + 1024 + aks + brow;                          \
        bf16x8 bf0 = LDSV(bbase), bf1 = LDSV(bbase + 16),                    \
               bf2 = LDSV(bbase + 32), bf3 = LDSV(bbase + 48);               \
        bf16x8 a0 = LDSV(abase), a1 = LDSV(abase + 16),                      \
               a2 = LDSV(abase + 32), a3 = LDSV(abase + 48);                 \
        bf16x8 a4 = LDSV(abase + 64), a5 = LDSV(abase + 80),                 \
               a6 = LDSV(abase + 96), a7 = LDSV(abase + 112);                \
        if (DO_STAGE) { STAGE_A((SB) * 2048, KT); STAGE_B((SB) * 2048, KT); }\
        if (VMSTR[0]) asm volatile(VMSTR ::: "memory");                      \
        __builtin_amdgcn_s_barrier();                                        \
        __builtin_amdgcn_s_setprio(1);                                       \
        MF(0, a0) MF(1, a1) MF(2, a2) MF(3, a3)                              \
        MF(4, a4) MF(5, a5) MF(6, a6) MF(7, a7)                              \
        __builtin_amdgcn_s_setprio(0);                                       \
    } while (0)

__global__ __launch_bounds__(512, 2) void moe_gemm_kernel(
    const unsigned short* __restrict__ xb,   // slab order [mt64][kt64][1024]
    const unsigned short* __restrict__ wbT,  // slab order [bx16][kt64][1024]
    const float* __restrict__ b_exp,         // [8][D_HID]
    const int* __restrict__ eidx,
    const float* __restrict__ s12,           // [N_TOK][2]
    float* __restrict__ out) {
    __shared__ __align__(16) short lds[4 * 2048 * 8];  // 128 KiB

    const int t512 = threadIdx.x;
    const int lane = t512 & 63;
    const int w    = t512 >> 6;
    const int wm   = w >> 2;
    const int wn   = w & 3;

    const int bid = blockIdx.x;
    const int xcd = bid & 7;
    const int jb  = bid >> 3;
    const int bx  = xcd * 2 + (jb & 1);
    const int by  = jb >> 1;
    const int mbase = by * 256;
    const int nbase = bx * 128;

    const unsigned short* gA0 = xb  + ((size_t)by * 64) * 8192 + t512 * 8;
    const unsigned short* gB0 = wbT + ((size_t)bx * 64) * 8192 + t512 * 8;

    const int aks  = (lane >> 4) * 256;
    const int arow = wm * 128 + (lane & 15);
    const int brow = wn * 64 + (lane & 15);

    f32x4 acc[8][4];
#pragma unroll
    for (int mi = 0; mi < 8; ++mi)
#pragma unroll
        for (int ni = 0; ni < 4; ++ni) acc[mi][ni] = (f32x4){0.f, 0.f, 0.f, 0.f};

    STAGE_A(0, 0);    STAGE_B(0, 0);
    STAGE_A(2048, 1); STAGE_B(2048, 1);
    STAGE_A(4096, 2); STAGE_B(4096, 2);
    asm volatile("s_waitcnt vmcnt(4)" ::: "memory");
    __builtin_amdgcn_s_barrier();

#pragma unroll 4
    for (int t = 0; t < 61; ++t) {
        TILE(t & 3, (t + 3) & 3, t + 3, 1, "s_waitcnt vmcnt(4)");
    }
    TILE(1, 0, 0, 0, "s_waitcnt vmcnt(4)");   // tile 61 (no wait in practice)
    TILE(2, 0, 0, 0, "s_waitcnt vmcnt(0)");   // tile 62: retire tile 63
    TILE(3, 0, 0, 0, "");                     // tile 63

    // -------- epilogue: combine experts through LDS (f32) --------
    __syncthreads();
    float* fl = (float*)lds;
    if (wn >= 2) {
        float* reg = fl + (wm * 2 + (wn - 2)) * 8192;   // [128][64]
#pragma unroll
        for (int mi = 0; mi < 8; ++mi)
#pragma unroll
            for (int ni = 0; ni < 4; ++ni)
#pragma unroll
                for (int j = 0; j < 4; ++j) {
                    int row_l = mi * 16 + ((lane >> 4) << 2) + j;
                    int col_l = ni * 16 + (lane & 15);
                    reg[row_l * 64 + col_l] = acc[mi][ni][j];
                }
    }
    __syncthreads();
    if (wn < 2) {
        const float* reg = fl + (wm * 2 + wn) * 8192;
        const int e0 = eidx[0], e1 = eidx[1];
        const float* bb0 = b_exp + (size_t)e0 * D_HID;
        const float* bb1 = b_exp + (size_t)e1 * D_HID;
        const float2* s12v = (const float2*)s12;
        int   cc[4];
        float b0c[4], b1c[4];
#pragma unroll
        for (int ni = 0; ni < 4; ++ni) {
            cc[ni]  = nbase + wn * 64 + ni * 16 + (lane & 15);
            b0c[ni] = bb0[cc[ni]];
            b1c[ni] = bb1[cc[ni]];
        }
#pragma unroll
        for (int mi = 0; mi < 8; ++mi)
#pragma unroll
            for (int j = 0; j < 4; ++j) {
                int row_l = mi * 16 + ((lane >> 4) << 2) + j;
                int r = mbase + wm * 128 + row_l;
                float2 s = s12v[r];
#pragma unroll
                for (int ni = 0; ni < 4; ++ni) {
                    float y1 = reg[row_l * 64 + ni * 16 + (lane & 15)];
                    out[(size_t)r * D_HID + cc[ni]] =
                        s.x * (acc[mi][ni][j] + b0c[ni]) + s.y * (y1 + b1c[ni]);
                }
            }
    }
}

// ---------------------------------------------------------------- launch --
extern "C" void kernel_launch(void* const* d_in, const int* in_sizes, int n_in,
                              void* d_out, int out_size, void* d_ws, size_t ws_size,
                              hipStream_t stream) {
    const float* x         = (const float*)d_in[0];
    const float* W_experts = (const float*)d_in[1];
    const float* b_experts = (const float*)d_in[2];
    const float* W_gate    = (const float*)d_in[3];
    const float* b_gate    = (const float*)d_in[4];
    float* out = (float*)d_out;

    char* ws = (char*)d_ws;
    float* s12  = (float*)ws;                                        // 128 KiB
    int*   eidx = (int*)(ws + 131072);
    unsigned short* xb  = (unsigned short*)(ws + 262144);            // 64 MiB
    unsigned short* wbT = (unsigned short*)(ws + 262144 + 67108864); // 16 MiB
    float* part = out;   // 4.2 MB gate partials in d_out scratch (GEMM
                         // fully overwrites out afterwards, every call)

    xconv3_kernel<<<512, 256, 0, stream>>>(x, W_gate, xb, part);
    gatefin_kernel<<<256, 256, 0, stream>>>(part, b_gate, s12, eidx);
    wconv_kernel<<<dim3(32, 32, 2), 256, 0, stream>>>(W_experts, eidx, wbT);
    moe_gemm_kernel<<<1024, 512, 0, stream>>>(xb, wbT, b_experts, eidx, s12, out);
}